// Round 12
// baseline (165.199 us; speedup 1.0000x reference)
//
#include <hip/hip_runtime.h>
#include <hip/hip_bf16.h>

typedef __attribute__((ext_vector_type(8))) short bf16x8;
typedef __attribute__((ext_vector_type(4))) float f32x4;

__device__ __forceinline__ ushort f2bf(float x) {
  unsigned u = __float_as_uint(x);
  u = (u + 0x7FFFu + ((u >> 16) & 1u)) >> 16;
  return (ushort)u;
}

// Kt[o][i] = bf16(K[i][o]);  K: [256][1024] f32, Kt: [1024][256] bf16
__global__ void WV_kconv(const float* __restrict__ K, ushort* __restrict__ Kt) {
  int f = (blockIdx.x * 256 + threadIdx.x) * 4;
  int o = f >> 8, i0 = f & 255;
  ushort4 w;
  w.x = f2bf(K[(size_t)(i0 + 0) * 1024 + o]);
  w.y = f2bf(K[(size_t)(i0 + 1) * 1024 + o]);
  w.z = f2bf(K[(size_t)(i0 + 2) * 1024 + o]);
  w.w = f2bf(K[(size_t)(i0 + 3) * 1024 + o]);
  *reinterpret_cast<ushort4*>(Kt + f) = w;
}

// Block (b,h): h = i-half. Stages A_b rows [h*128, h*128+128) -> 64 KB LDS.
// 8 waves; wave owns o-strip of 128 (og2 x ot4 x 16).
// Register budget: acc[2][4]=32 acc-regs + ~60 arch regs => total <~100
// <= 128 => 4+ waves/SIMD => 2 blocks/CU resident (R10 failed at 132 total).
__global__ __launch_bounds__(512, 2) void WV_main(
    const float* __restrict__ A, const ushort* __restrict__ Kt,
    float* __restrict__ out) {
  __shared__ short As[128 * 256];  // 64 KB bf16, XOR-swizzled rows
  const int bh = blockIdx.x;
  const int b = bh >> 1, h = bh & 1;
  const float* Ah = A + (size_t)b * 65536 + (size_t)h * 32768;
  const int t = threadIdx.x;

  // ---- stage 128 rows: fp32 -> bf16, swizzle byte ^= (row&7)<<4 ----
  #pragma unroll 1
  for (int it = 0; it < 8; ++it) {
    int c = it * 512 + t;  // chunk of 8 floats
    int m = c >> 5;        // local row 0..127
    int s = c & 31;        // 16B slot within row
    const float4* p = reinterpret_cast<const float4*>(Ah) + c * 2;
    float4 v0 = p[0], v1 = p[1];
    bf16x8 w;
    w[0] = (short)f2bf(v0.x); w[1] = (short)f2bf(v0.y);
    w[2] = (short)f2bf(v0.z); w[3] = (short)f2bf(v0.w);
    w[4] = (short)f2bf(v1.x); w[5] = (short)f2bf(v1.y);
    w[6] = (short)f2bf(v1.z); w[7] = (short)f2bf(v1.w);
    int byteoff = m * 512 + ((s * 16) ^ ((m & 7) << 4));
    *reinterpret_cast<bf16x8*>(reinterpret_cast<char*>(As) + byteoff) = w;
  }
  __syncthreads();

  const int wave = t >> 6, lane = t & 63;
  const int lo = lane & 15;   // row (A) / col (B,D) within tile
  const int hi = lane >> 4;   // 0..3: k-group (A,B) / row-group (D)
  const int wob = wave * 128; // wave's o-strip base

  #pragma unroll 1
  for (int og = 0; og < 2; ++og) {
    float oseg[4] = {0.f, 0.f, 0.f, 0.f};

    #pragma unroll 1
    for (int ig = 0; ig < 4; ++ig) {  // 4 groups x 2 i-tiles
      f32x4 acc[2][4];
      #pragma unroll
      for (int a1 = 0; a1 < 2; ++a1)
        #pragma unroll
        for (int a2 = 0; a2 < 4; ++a2)
          acc[a1][a2] = (f32x4){0.f, 0.f, 0.f, 0.f};

      // lane's Kt base: row (wob+og*64+lo), col hi*8; ot adds 16 rows, ks adds 32 cols
      const ushort* KtB = Kt + (size_t)(wob + og * 64 + lo) * 256 + hi * 8;

      #pragma unroll 1
      for (int ks = 0; ks < 8; ++ks) {
        bf16x8 Bc[4];
        #pragma unroll
        for (int ot = 0; ot < 4; ++ot)
          Bc[ot] = *reinterpret_cast<const bf16x8*>(KtB + ot * 4096 + ks * 32);
        const int kk = ks * 32 + hi * 8;
        #pragma unroll
        for (int itl = 0; itl < 2; ++itl) {
          int m = ig * 32 + itl * 16 + lo;
          int byteoff = m * 512 + ((kk * 2) ^ ((m & 7) << 4));
          bf16x8 Af = *reinterpret_cast<const bf16x8*>(
              reinterpret_cast<char*>(As) + byteoff);
          #pragma unroll
          for (int ot = 0; ot < 4; ++ot)
            acc[itl][ot] = __builtin_amdgcn_mfma_f32_16x16x32_bf16(
                Af, Bc[ot], acc[itl][ot], 0, 0, 0);
        }
      }

      // epilogue: oseg[ot] += sum over this ig's 32 i-rows (global i = h*128+...)
      #pragma unroll
      for (int itl = 0; itl < 2; ++itl) {
        const int i0 = h * 128 + ig * 32 + itl * 16 + hi * 4;
        #pragma unroll
        for (int ot = 0; ot < 4; ++ot) {
          int n = wob + og * 64 + ot * 16 + lo;
          ushort4 wv = *reinterpret_cast<const ushort4*>(Kt + (size_t)n * 256 + i0);
          f32x4 a = acc[itl][ot];
          float s = __uint_as_float((unsigned)wv.x << 16) * a[0]
                  + __uint_as_float((unsigned)wv.y << 16) * a[1]
                  + __uint_as_float((unsigned)wv.z << 16) * a[2]
                  + __uint_as_float((unsigned)wv.w << 16) * a[3];
          s += __shfl_xor(s, 16);
          s += __shfl_xor(s, 32);
          oseg[ot] += s;
        }
      }
    }

    if (lane < 16) {
      #pragma unroll
      for (int ot = 0; ot < 4; ++ot)
        atomicAdd(&out[(size_t)b * 1024 + wob + og * 64 + ot * 16 + lane],
                  oseg[ot]);
    }
  }
}

extern "C" void kernel_launch(void* const* d_in, const int* in_sizes, int n_in,
                              void* d_out, int out_size, void* d_ws, size_t ws_size,
                              hipStream_t stream) {
  const float* A = (const float*)d_in[0];   // (256,256,256) f32
  const float* K = (const float*)d_in[1];   // (256,1024)   f32
  float* out = (float*)d_out;               // (256,1024)   f32
  ushort* Kt = (ushort*)d_ws;               // (1024,256)   bf16
  hipMemsetAsync(d_out, 0, (size_t)out_size * sizeof(float), stream);
  WV_kconv<<<256, 256, 0, stream>>>(K, Kt);
  WV_main<<<512, 512, 0, stream>>>(A, Kt, out);
}

// Round 13
// 69.248 us; speedup vs baseline: 2.3856x; 2.3856x over previous
//
#include <hip/hip_runtime.h>
#include <hip/hip_bf16.h>

typedef __attribute__((ext_vector_type(8))) short bf16x8;
typedef __attribute__((ext_vector_type(4))) float f32x4;

__device__ __forceinline__ ushort f2bf(float x) {
  unsigned u = __float_as_uint(x);
  u = (u + 0x7FFFu + ((u >> 16) & 1u)) >> 16;
  return (ushort)u;
}

// Pack K (f32 [256][1024]) into MFMA-fragment order:
// chunk c = (otile 0..63, ks 0..7, lane 0..63); chunk holds 8 bf16:
//   o = otile*16 + (lane&15), k = ks*32 + (lane>>4)*8 + e
// So a wave's B-fragment load is lane-contiguous (1 transaction).
__global__ void WV_kconv(const float* __restrict__ K, ushort* __restrict__ KtP) {
  int c = blockIdx.x * 256 + threadIdx.x;  // 0..32767
  int otile = c >> 9, ks = (c >> 6) & 7, lane = c & 63;
  int o = otile * 16 + (lane & 15);
  int kb = ks * 32 + (lane >> 4) * 8;
  bf16x8 w;
  #pragma unroll
  for (int e = 0; e < 8; ++e)
    w[e] = (short)f2bf(K[(size_t)(kb + e) * 1024 + o]);
  *reinterpret_cast<bf16x8*>(KtP + (size_t)c * 8) = w;
}

// Block (b,h): h = i-half. Stages A_b rows [h*128,h*128+128) -> 64 KB LDS.
// 8 waves; wave owns o-strip of 128. acc[2][4] (32 acc regs) -> 2 blk/CU.
// All Kt accesses (B-fragments AND epilogue weights) go through the packed
// KtP layout -> coalesced 1-2 transactions per wave-load (R12 post-mortem:
// the old row-gather was 16 transactions/load and serialized the TA pipe).
__global__ __launch_bounds__(512, 2) void WV_main(
    const float* __restrict__ A, const ushort* __restrict__ KtP,
    float* __restrict__ out) {
  __shared__ short As[128 * 256];  // 64 KB bf16, XOR-swizzled rows
  const int bh = blockIdx.x;
  const int b = bh >> 1, h = bh & 1;
  const float* Ah = A + (size_t)b * 65536 + (size_t)h * 32768;
  const int t = threadIdx.x;

  // ---- stage 128 rows: fp32 -> bf16, swizzle byte ^= (row&7)<<4 ----
  #pragma unroll 1
  for (int it = 0; it < 8; ++it) {
    int c = it * 512 + t;  // chunk of 8 floats
    int m = c >> 5;        // local row 0..127
    int s = c & 31;        // 16B slot within row
    const float4* p = reinterpret_cast<const float4*>(Ah) + c * 2;
    float4 v0 = p[0], v1 = p[1];
    bf16x8 w;
    w[0] = (short)f2bf(v0.x); w[1] = (short)f2bf(v0.y);
    w[2] = (short)f2bf(v0.z); w[3] = (short)f2bf(v0.w);
    w[4] = (short)f2bf(v1.x); w[5] = (short)f2bf(v1.y);
    w[6] = (short)f2bf(v1.z); w[7] = (short)f2bf(v1.w);
    int byteoff = m * 512 + ((s * 16) ^ ((m & 7) << 4));
    *reinterpret_cast<bf16x8*>(reinterpret_cast<char*>(As) + byteoff) = w;
  }
  __syncthreads();

  const int wave = t >> 6, lane = t & 63;
  const int lo = lane & 15;   // row (A) / col (B,D) within tile
  const int hi = lane >> 4;   // 0..3: k-group (A,B) / row-group (D)
  const int wob = wave * 128; // wave's o-strip base

  #pragma unroll 1
  for (int og = 0; og < 2; ++og) {
    float oseg[4] = {0.f, 0.f, 0.f, 0.f};
    const int otb = wave * 8 + og * 4;  // global o-tile base for this og

    #pragma unroll 1
    for (int ig = 0; ig < 4; ++ig) {  // 4 groups x 2 i-tiles
      f32x4 acc[2][4];
      #pragma unroll
      for (int a1 = 0; a1 < 2; ++a1)
        #pragma unroll
        for (int a2 = 0; a2 < 4; ++a2)
          acc[a1][a2] = (f32x4){0.f, 0.f, 0.f, 0.f};

      #pragma unroll 1
      for (int ks = 0; ks < 8; ++ks) {
        bf16x8 Bc[4];
        #pragma unroll
        for (int ot = 0; ot < 4; ++ot)
          Bc[ot] = *reinterpret_cast<const bf16x8*>(
              KtP + ((size_t)((otb + ot) * 8 + ks) * 64 + lane) * 8);
        const int kk = ks * 32 + hi * 8;
        #pragma unroll
        for (int itl = 0; itl < 2; ++itl) {
          int m = ig * 32 + itl * 16 + lo;
          int byteoff = m * 512 + ((kk * 2) ^ ((m & 7) << 4));
          bf16x8 Af = *reinterpret_cast<const bf16x8*>(
              reinterpret_cast<char*>(As) + byteoff);
          #pragma unroll
          for (int ot = 0; ot < 4; ++ot)
            acc[itl][ot] = __builtin_amdgcn_mfma_f32_16x16x32_bf16(
                Af, Bc[ot], acc[itl][ot], 0, 0, 0);
        }
      }

      // epilogue: oseg[ot] += sum over this ig's 32 i-rows.
      // Weights K[i0+r][n] come from KtP: chunk (otb+ot, kse, lo+g*16),
      // elems e..e+3 where kse=h*4+ig, g=itl*2+(hi>>1), e=(hi&1)*4.
      const int kse = h * 4 + ig;
      #pragma unroll
      for (int itl = 0; itl < 2; ++itl) {
        const int g = itl * 2 + (hi >> 1);
        const int e = (hi & 1) * 4;
        #pragma unroll
        for (int ot = 0; ot < 4; ++ot) {
          const ushort* wp = KtP +
              ((size_t)((otb + ot) * 8 + kse) * 64 + lo + g * 16) * 8 + e;
          ushort4 wv = *reinterpret_cast<const ushort4*>(wp);
          f32x4 a = acc[itl][ot];
          float s = __uint_as_float((unsigned)wv.x << 16) * a[0]
                  + __uint_as_float((unsigned)wv.y << 16) * a[1]
                  + __uint_as_float((unsigned)wv.z << 16) * a[2]
                  + __uint_as_float((unsigned)wv.w << 16) * a[3];
          s += __shfl_xor(s, 16);
          s += __shfl_xor(s, 32);
          oseg[ot] += s;
        }
      }
    }

    if (lane < 16) {
      #pragma unroll
      for (int ot = 0; ot < 4; ++ot)
        atomicAdd(&out[(size_t)b * 1024 + wob + og * 64 + ot * 16 + lane],
                  oseg[ot]);
    }
  }
}

extern "C" void kernel_launch(void* const* d_in, const int* in_sizes, int n_in,
                              void* d_out, int out_size, void* d_ws, size_t ws_size,
                              hipStream_t stream) {
  const float* A = (const float*)d_in[0];   // (256,256,256) f32
  const float* K = (const float*)d_in[1];   // (256,1024)   f32
  float* out = (float*)d_out;               // (256,1024)   f32
  ushort* KtP = (ushort*)d_ws;              // packed (64,8,64,8) bf16
  hipMemsetAsync(d_out, 0, (size_t)out_size * sizeof(float), stream);
  WV_kconv<<<128, 256, 0, stream>>>(K, KtP);
  WV_main<<<512, 512, 0, stream>>>(A, KtP, out);
}

// Round 14
// 66.093 us; speedup vs baseline: 2.4995x; 1.0477x over previous
//
#include <hip/hip_runtime.h>
#include <hip/hip_bf16.h>

typedef __attribute__((ext_vector_type(8))) short bf16x8;
typedef __attribute__((ext_vector_type(4))) float f32x4;

__device__ __forceinline__ ushort f2bf(float x) {
  unsigned u = __float_as_uint(x);
  u = (u + 0x7FFFu + ((u >> 16) & 1u)) >> 16;
  return (ushort)u;
}

// Pack K (f32 [256][1024]) into MFMA-fragment order:
// chunk c = (otile 0..63, ks 0..7, lane 0..63); chunk holds 8 bf16:
//   o = otile*16 + (lane&15), k = ks*32 + (lane>>4)*8 + e
__global__ void WV_kconv(const float* __restrict__ K, ushort* __restrict__ KtP) {
  int c = blockIdx.x * 256 + threadIdx.x;  // 0..32767
  int otile = c >> 9, ks = (c >> 6) & 7, lane = c & 63;
  int o = otile * 16 + (lane & 15);
  int kb = ks * 32 + (lane >> 4) * 8;
  bf16x8 w;
  #pragma unroll
  for (int e = 0; e < 8; ++e)
    w[e] = (short)f2bf(K[(size_t)(kb + e) * 1024 + o]);
  *reinterpret_cast<bf16x8*>(KtP + (size_t)c * 8) = w;
}

// Block (b,h): h = i-half. A rows [h*128,h*128+128) -> 64 KB LDS (bf16,
// XOR-swizzled). 8 waves; wave owns o-strip of 128.
// R14 change vs R13: acc[4][4] (64 regs) + ig2 x itl4 -> each Bc[4] load
// amortized over 4 i-tiles (was 2): Kt loads 256->128/wave, ks-iters
// 64->32. Budget: ~52 arch + 64 acc = 116 <= 128 -> 2 blocks/CU kept.
__global__ __launch_bounds__(512, 2) void WV_main(
    const float* __restrict__ A, const ushort* __restrict__ KtP,
    float* __restrict__ out) {
  __shared__ short As[128 * 256];  // 64 KB
  const int bh = blockIdx.x;
  const int b = bh >> 1, h = bh & 1;
  const float* Ah = A + (size_t)b * 65536 + (size_t)h * 32768;
  const int t = threadIdx.x;

  // ---- stage 128 rows: fp32 -> bf16, swizzle byte ^= (row&7)<<4 ----
  #pragma unroll 1
  for (int it = 0; it < 8; ++it) {
    int c = it * 512 + t;  // chunk of 8 floats
    int m = c >> 5;        // local row 0..127
    int s = c & 31;        // 16B slot within row
    const float4* p = reinterpret_cast<const float4*>(Ah) + c * 2;
    float4 v0 = p[0], v1 = p[1];
    bf16x8 w;
    w[0] = (short)f2bf(v0.x); w[1] = (short)f2bf(v0.y);
    w[2] = (short)f2bf(v0.z); w[3] = (short)f2bf(v0.w);
    w[4] = (short)f2bf(v1.x); w[5] = (short)f2bf(v1.y);
    w[6] = (short)f2bf(v1.z); w[7] = (short)f2bf(v1.w);
    int byteoff = m * 512 + ((s * 16) ^ ((m & 7) << 4));
    *reinterpret_cast<bf16x8*>(reinterpret_cast<char*>(As) + byteoff) = w;
  }
  __syncthreads();

  const int wave = t >> 6, lane = t & 63;
  const int lo = lane & 15;   // col within tile (B,D) / row (A)
  const int hi = lane >> 4;   // 0..3
  const int wob = wave * 128;

  #pragma unroll 1
  for (int og = 0; og < 2; ++og) {
    float oseg[4] = {0.f, 0.f, 0.f, 0.f};
    const int otb = wave * 8 + og * 4;  // o-tile base

    #pragma unroll 1
    for (int ig = 0; ig < 2; ++ig) {  // 2 groups x 4 i-tiles
      f32x4 acc[4][4];
      #pragma unroll
      for (int a1 = 0; a1 < 4; ++a1)
        #pragma unroll
        for (int a2 = 0; a2 < 4; ++a2)
          acc[a1][a2] = (f32x4){0.f, 0.f, 0.f, 0.f};

      #pragma unroll 1
      for (int ks = 0; ks < 8; ++ks) {
        bf16x8 Bc[4];
        #pragma unroll
        for (int ot = 0; ot < 4; ++ot)
          Bc[ot] = *reinterpret_cast<const bf16x8*>(
              KtP + ((size_t)((otb + ot) * 8 + ks) * 64 + lane) * 8);
        const int kk = ks * 32 + hi * 8;
        #pragma unroll
        for (int itl = 0; itl < 4; ++itl) {
          int m = ig * 64 + itl * 16 + lo;
          int byteoff = m * 512 + ((kk * 2) ^ ((m & 7) << 4));
          bf16x8 Af = *reinterpret_cast<const bf16x8*>(
              reinterpret_cast<char*>(As) + byteoff);
          #pragma unroll
          for (int ot = 0; ot < 4; ++ot)
            acc[itl][ot] = __builtin_amdgcn_mfma_f32_16x16x32_bf16(
                Af, Bc[ot], acc[itl][ot], 0, 0, 0);
        }
      }

      // epilogue: weights K[i0..i0+3][o(lane)] from KtP packed layout.
      // i0 = h*128+ig*64+itl*16+hi*4; kse = h*4+ig*2+(itl>>1),
      // g = (itl&1)*2+(hi>>1), e = (hi&1)*4  (kse*32+g*8+e == i0).
      #pragma unroll
      for (int itl = 0; itl < 4; ++itl) {
        const int kse = h * 4 + ig * 2 + (itl >> 1);
        const int g = (itl & 1) * 2 + (hi >> 1);
        const int e = (hi & 1) * 4;
        #pragma unroll
        for (int ot = 0; ot < 4; ++ot) {
          const ushort* wp = KtP +
              ((size_t)((otb + ot) * 8 + kse) * 64 + lo + g * 16) * 8 + e;
          ushort4 wv = *reinterpret_cast<const ushort4*>(wp);
          f32x4 a = acc[itl][ot];
          float s = __uint_as_float((unsigned)wv.x << 16) * a[0]
                  + __uint_as_float((unsigned)wv.y << 16) * a[1]
                  + __uint_as_float((unsigned)wv.z << 16) * a[2]
                  + __uint_as_float((unsigned)wv.w << 16) * a[3];
          s += __shfl_xor(s, 16);
          s += __shfl_xor(s, 32);
          oseg[ot] += s;
        }
      }
    }

    if (lane < 16) {
      #pragma unroll
      for (int ot = 0; ot < 4; ++ot)
        atomicAdd(&out[(size_t)b * 1024 + wob + og * 64 + ot * 16 + lane],
                  oseg[ot]);
    }
  }
}

extern "C" void kernel_launch(void* const* d_in, const int* in_sizes, int n_in,
                              void* d_out, int out_size, void* d_ws, size_t ws_size,
                              hipStream_t stream) {
  const float* A = (const float*)d_in[0];   // (256,256,256) f32
  const float* K = (const float*)d_in[1];   // (256,1024)   f32
  float* out = (float*)d_out;               // (256,1024)   f32
  ushort* KtP = (ushort*)d_ws;              // packed (64,8,64,8) bf16
  hipMemsetAsync(d_out, 0, (size_t)out_size * sizeof(float), stream);
  WV_kconv<<<128, 256, 0, stream>>>(K, KtP);
  WV_main<<<512, 512, 0, stream>>>(A, KtP, out);
}

// Round 15
// 58.342 us; speedup vs baseline: 2.8316x; 1.1329x over previous
//
#include <hip/hip_runtime.h>
#include <hip/hip_bf16.h>

typedef __attribute__((ext_vector_type(8))) short bf16x8;
typedef __attribute__((ext_vector_type(4))) float f32x4;

__device__ __forceinline__ ushort f2bf(float x) {
  unsigned u = __float_as_uint(x);
  u = (u + 0x7FFFu + ((u >> 16) & 1u)) >> 16;
  return (ushort)u;
}

// Pack K (f32 [256][1024]) into MFMA-fragment order:
// chunk c = (otile 0..63, ks 0..7, lane 0..63); chunk holds 8 bf16:
//   o = otile*16 + (lane&15), k = ks*32 + (lane>>4)*8 + e
__global__ void WV_kconv(const float* __restrict__ K, ushort* __restrict__ KtP) {
  int c = blockIdx.x * 256 + threadIdx.x;  // 0..32767
  int otile = c >> 9, ks = (c >> 6) & 7, lane = c & 63;
  int o = otile * 16 + (lane & 15);
  int kb = ks * 32 + (lane >> 4) * 8;
  bf16x8 w;
  #pragma unroll
  for (int e = 0; e < 8; ++e)
    w[e] = (short)f2bf(K[(size_t)(kb + e) * 1024 + o]);
  *reinterpret_cast<bf16x8*>(KtP + (size_t)c * 8) = w;
}

// Block (b,h): h = i-half. A rows [h*128,h*128+128) -> 64 KB LDS (bf16,
// XOR-swizzled). 8 waves; wave owns o-strip of 128.
// R15 change vs R14: ks pipelined 2-wide — prefetch next ks-PAIR's 8 Bc
// fragments before the current pair's 32 MFMAs, so vmcnt-wait overlaps
// the MFMA block (R14 post-mortem: 78-cyc MFMA vs ~300-cyc exposed load
// latency per iter => 20% duty). Regs ~158 -> still 2 waves/SIMD.
__global__ __launch_bounds__(512, 1) void WV_main(
    const float* __restrict__ A, const ushort* __restrict__ KtP,
    float* __restrict__ out) {
  __shared__ short As[128 * 256];  // 64 KB
  const int bh = blockIdx.x;
  const int b = bh >> 1, h = bh & 1;
  const float* Ah = A + (size_t)b * 65536 + (size_t)h * 32768;
  const int t = threadIdx.x;

  // ---- stage 128 rows: fp32 -> bf16, swizzle byte ^= (row&7)<<4 ----
  #pragma unroll 1
  for (int it = 0; it < 8; ++it) {
    int c = it * 512 + t;  // chunk of 8 floats
    int m = c >> 5;        // local row 0..127
    int s = c & 31;        // 16B slot within row
    const float4* p = reinterpret_cast<const float4*>(Ah) + c * 2;
    float4 v0 = p[0], v1 = p[1];
    bf16x8 w;
    w[0] = (short)f2bf(v0.x); w[1] = (short)f2bf(v0.y);
    w[2] = (short)f2bf(v0.z); w[3] = (short)f2bf(v0.w);
    w[4] = (short)f2bf(v1.x); w[5] = (short)f2bf(v1.y);
    w[6] = (short)f2bf(v1.z); w[7] = (short)f2bf(v1.w);
    int byteoff = m * 512 + ((s * 16) ^ ((m & 7) << 4));
    *reinterpret_cast<bf16x8*>(reinterpret_cast<char*>(As) + byteoff) = w;
  }
  __syncthreads();

  const int wave = t >> 6, lane = t & 63;
  const int lo = lane & 15;   // col within tile (B,D) / row (A)
  const int hi = lane >> 4;   // 0..3
  const int wob = wave * 128;

  #pragma unroll 1
  for (int og = 0; og < 2; ++og) {
    float oseg[4] = {0.f, 0.f, 0.f, 0.f};
    const int otb = wave * 8 + og * 4;  // o-tile base

    #pragma unroll 1
    for (int ig = 0; ig < 2; ++ig) {  // 2 groups x 4 i-tiles
      f32x4 acc[4][4];
      #pragma unroll
      for (int a1 = 0; a1 < 4; ++a1)
        #pragma unroll
        for (int a2 = 0; a2 < 4; ++a2)
          acc[a1][a2] = (f32x4){0.f, 0.f, 0.f, 0.f};

      // prologue: load ks-pair 0 (ks = 0,1)
      bf16x8 Bc[2][4];
      #pragma unroll
      for (int kh = 0; kh < 2; ++kh)
        #pragma unroll
        for (int ot = 0; ot < 4; ++ot)
          Bc[kh][ot] = *reinterpret_cast<const bf16x8*>(
              KtP + ((size_t)((otb + ot) * 8 + kh) * 64 + lane) * 8);

      #pragma unroll 1
      for (int kp = 0; kp < 4; ++kp) {
        bf16x8 Bn[2][4];
        if (kp < 3) {  // prefetch next pair (wave-uniform branch)
          #pragma unroll
          for (int kh = 0; kh < 2; ++kh)
            #pragma unroll
            for (int ot = 0; ot < 4; ++ot)
              Bn[kh][ot] = *reinterpret_cast<const bf16x8*>(
                  KtP + ((size_t)((otb + ot) * 8 + (kp * 2 + 2 + kh)) * 64
                         + lane) * 8);
        }
        #pragma unroll
        for (int kh = 0; kh < 2; ++kh) {
          const int kk = (kp * 2 + kh) * 32 + hi * 8;
          #pragma unroll
          for (int itl = 0; itl < 4; ++itl) {
            int m = ig * 64 + itl * 16 + lo;
            int byteoff = m * 512 + ((kk * 2) ^ ((m & 7) << 4));
            bf16x8 Af = *reinterpret_cast<const bf16x8*>(
                reinterpret_cast<char*>(As) + byteoff);
            #pragma unroll
            for (int ot = 0; ot < 4; ++ot)
              acc[itl][ot] = __builtin_amdgcn_mfma_f32_16x16x32_bf16(
                  Af, Bc[kh][ot], acc[itl][ot], 0, 0, 0);
          }
        }
        if (kp < 3) {
          #pragma unroll
          for (int kh = 0; kh < 2; ++kh)
            #pragma unroll
            for (int ot = 0; ot < 4; ++ot)
              Bc[kh][ot] = Bn[kh][ot];
        }
      }

      // epilogue: weights K[i0..i0+3][o(lane)] from KtP packed layout.
      // i0 = h*128+ig*64+itl*16+hi*4; kse = h*4+ig*2+(itl>>1),
      // g = (itl&1)*2+(hi>>1), e = (hi&1)*4  (kse*32+g*8+e == i0).
      #pragma unroll
      for (int itl = 0; itl < 4; ++itl) {
        const int kse = h * 4 + ig * 2 + (itl >> 1);
        const int g = (itl & 1) * 2 + (hi >> 1);
        const int e = (hi & 1) * 4;
        #pragma unroll
        for (int ot = 0; ot < 4; ++ot) {
          const ushort* wp = KtP +
              ((size_t)((otb + ot) * 8 + kse) * 64 + lo + g * 16) * 8 + e;
          ushort4 wv = *reinterpret_cast<const ushort4*>(wp);
          f32x4 a = acc[itl][ot];
          float s = __uint_as_float((unsigned)wv.x << 16) * a[0]
                  + __uint_as_float((unsigned)wv.y << 16) * a[1]
                  + __uint_as_float((unsigned)wv.z << 16) * a[2]
                  + __uint_as_float((unsigned)wv.w << 16) * a[3];
          s += __shfl_xor(s, 16);
          s += __shfl_xor(s, 32);
          oseg[ot] += s;
        }
      }
    }

    if (lane < 16) {
      #pragma unroll
      for (int ot = 0; ot < 4; ++ot)
        atomicAdd(&out[(size_t)b * 1024 + wob + og * 64 + ot * 16 + lane],
                  oseg[ot]);
    }
  }
}

extern "C" void kernel_launch(void* const* d_in, const int* in_sizes, int n_in,
                              void* d_out, int out_size, void* d_ws, size_t ws_size,
                              hipStream_t stream) {
  const float* A = (const float*)d_in[0];   // (256,256,256) f32
  const float* K = (const float*)d_in[1];   // (256,1024)   f32
  float* out = (float*)d_out;               // (256,1024)   f32
  ushort* KtP = (ushort*)d_ws;              // packed (64,8,64,8) bf16
  hipMemsetAsync(d_out, 0, (size_t)out_size * sizeof(float), stream);
  WV_kconv<<<128, 256, 0, stream>>>(K, KtP);
  WV_main<<<512, 512, 0, stream>>>(A, KtP, out);
}

// Round 16
// 54.818 us; speedup vs baseline: 3.0136x; 1.0643x over previous
//
#include <hip/hip_runtime.h>
#include <hip/hip_bf16.h>

typedef __attribute__((ext_vector_type(8))) short bf16x8;
typedef __attribute__((ext_vector_type(4))) float f32x4;

__device__ __forceinline__ ushort f2bf(float x) {
  unsigned u = __float_as_uint(x);
  u = (u + 0x7FFFu + ((u >> 16) & 1u)) >> 16;
  return (ushort)u;
}

// Pack K (f32 [256][1024]) into MFMA-fragment order:
// chunk c = (otile 0..63, ks 0..7, lane 0..63); chunk holds 8 bf16:
//   o = otile*16 + (lane&15), k = ks*32 + (lane>>4)*8 + e
__global__ void WV_kconv(const float* __restrict__ K, ushort* __restrict__ KtP) {
  int c = blockIdx.x * 256 + threadIdx.x;  // 0..32767
  int otile = c >> 9, ks = (c >> 6) & 7, lane = c & 63;
  int o = otile * 16 + (lane & 15);
  int kb = ks * 32 + (lane >> 4) * 8;
  bf16x8 w;
  #pragma unroll
  for (int e = 0; e < 8; ++e)
    w[e] = (short)f2bf(K[(size_t)(kb + e) * 1024 + o]);
  *reinterpret_cast<bf16x8*>(KtP + (size_t)c * 8) = w;
}

// Block (b,h): h = i-QUARTER (64 rows) -> 32 KB LDS -> 2 blocks/CU.
// R16 vs R15: i-range 128->64 kills the ig loop: acc[4][4] spans ALL
// 4 i-tiles, so Kt loads/wave halve (128->64) AND regs fit 4 waves/SIMD
// (acc 64 + Bc/Bn 32 + misc ~25 <= 128). TLP x2 + 1-ks-ahead prefetch
// now stack instead of trading off (R15 post-mortem).
__global__ __launch_bounds__(512, 2) void WV_main(
    const float* __restrict__ A, const ushort* __restrict__ KtP,
    float* __restrict__ out) {
  __shared__ short As[64 * 256];  // 32 KB
  const int bh = blockIdx.x;
  const int b = bh >> 2, h = bh & 3;
  const float* Ah = A + (size_t)b * 65536 + (size_t)h * 16384;
  const int t = threadIdx.x;

  // ---- stage 64 rows: fp32 -> bf16, swizzle byte ^= (row&7)<<4 ----
  #pragma unroll 1
  for (int it = 0; it < 4; ++it) {
    int c = it * 512 + t;  // chunk of 8 floats
    int m = c >> 5;        // local row 0..63
    int s = c & 31;        // 16B slot within row
    const float4* p = reinterpret_cast<const float4*>(Ah) + c * 2;
    float4 v0 = p[0], v1 = p[1];
    bf16x8 w;
    w[0] = (short)f2bf(v0.x); w[1] = (short)f2bf(v0.y);
    w[2] = (short)f2bf(v0.z); w[3] = (short)f2bf(v0.w);
    w[4] = (short)f2bf(v1.x); w[5] = (short)f2bf(v1.y);
    w[6] = (short)f2bf(v1.z); w[7] = (short)f2bf(v1.w);
    int byteoff = m * 512 + ((s * 16) ^ ((m & 7) << 4));
    *reinterpret_cast<bf16x8*>(reinterpret_cast<char*>(As) + byteoff) = w;
  }
  __syncthreads();

  const int wave = t >> 6, lane = t & 63;
  const int lo = lane & 15;   // col within tile (B,D) / row (A)
  const int hi = lane >> 4;   // 0..3
  const int wob = wave * 128;

  #pragma unroll 1
  for (int og = 0; og < 2; ++og) {
    float oseg[4] = {0.f, 0.f, 0.f, 0.f};
    const int otb = wave * 8 + og * 4;  // o-tile base

    f32x4 acc[4][4];
    #pragma unroll
    for (int a1 = 0; a1 < 4; ++a1)
      #pragma unroll
      for (int a2 = 0; a2 < 4; ++a2)
        acc[a1][a2] = (f32x4){0.f, 0.f, 0.f, 0.f};

    // prologue: load ks=0 fragments
    bf16x8 Bc[4];
    #pragma unroll
    for (int ot = 0; ot < 4; ++ot)
      Bc[ot] = *reinterpret_cast<const bf16x8*>(
          KtP + ((size_t)((otb + ot) * 8 + 0) * 64 + lane) * 8);

    #pragma unroll 1
    for (int ks = 0; ks < 8; ++ks) {
      bf16x8 Bn[4];
      if (ks < 7) {  // prefetch next ks (wave-uniform branch)
        #pragma unroll
        for (int ot = 0; ot < 4; ++ot)
          Bn[ot] = *reinterpret_cast<const bf16x8*>(
              KtP + ((size_t)((otb + ot) * 8 + ks + 1) * 64 + lane) * 8);
      }
      const int kk = ks * 32 + hi * 8;
      #pragma unroll
      for (int itl = 0; itl < 4; ++itl) {
        int m = itl * 16 + lo;
        int byteoff = m * 512 + ((kk * 2) ^ ((m & 7) << 4));
        bf16x8 Af = *reinterpret_cast<const bf16x8*>(
            reinterpret_cast<char*>(As) + byteoff);
        #pragma unroll
        for (int ot = 0; ot < 4; ++ot)
          acc[itl][ot] = __builtin_amdgcn_mfma_f32_16x16x32_bf16(
              Af, Bc[ot], acc[itl][ot], 0, 0, 0);
      }
      if (ks < 7) {
        #pragma unroll
        for (int ot = 0; ot < 4; ++ot) Bc[ot] = Bn[ot];
      }
    }

    // epilogue: weights K[i0..i0+3][o(lane)] from KtP packed layout.
    // i0 = h*64+itl*16+hi*4 = kse*32+g*8+e with kse = h*2+(itl>>1),
    // g = (itl&1)*2+(hi>>1), e = (hi&1)*4.
    #pragma unroll
    for (int itl = 0; itl < 4; ++itl) {
      const int kse = h * 2 + (itl >> 1);
      const int g = (itl & 1) * 2 + (hi >> 1);
      const int e = (hi & 1) * 4;
      #pragma unroll
      for (int ot = 0; ot < 4; ++ot) {
        const ushort* wp = KtP +
            ((size_t)((otb + ot) * 8 + kse) * 64 + lo + g * 16) * 8 + e;
        ushort4 wv = *reinterpret_cast<const ushort4*>(wp);
        f32x4 a = acc[itl][ot];
        float s = __uint_as_float((unsigned)wv.x << 16) * a[0]
                + __uint_as_float((unsigned)wv.y << 16) * a[1]
                + __uint_as_float((unsigned)wv.z << 16) * a[2]
                + __uint_as_float((unsigned)wv.w << 16) * a[3];
        s += __shfl_xor(s, 16);
        s += __shfl_xor(s, 32);
        oseg[ot] += s;
      }
    }

    if (lane < 16) {
      #pragma unroll
      for (int ot = 0; ot < 4; ++ot)
        atomicAdd(&out[(size_t)b * 1024 + wob + og * 64 + ot * 16 + lane],
                  oseg[ot]);
    }
  }
}

extern "C" void kernel_launch(void* const* d_in, const int* in_sizes, int n_in,
                              void* d_out, int out_size, void* d_ws, size_t ws_size,
                              hipStream_t stream) {
  const float* A = (const float*)d_in[0];   // (256,256,256) f32
  const float* K = (const float*)d_in[1];   // (256,1024)   f32
  float* out = (float*)d_out;               // (256,1024)   f32
  ushort* KtP = (ushort*)d_ws;              // packed (64,8,64,8) bf16
  hipMemsetAsync(d_out, 0, (size_t)out_size * sizeof(float), stream);
  WV_kconv<<<128, 256, 0, stream>>>(K, KtP);
  WV_main<<<1024, 512, 0, stream>>>(A, KtP, out);
}